// Round 10
// baseline (180.350 us; speedup 1.0000x reference)
//
#include <hip/hip_runtime.h>
#include <hip/hip_bf16.h>

// Problem constants (B=2, C=128, H=W=56)
#define BATCH 2
#define CH    128
#define HH    56
#define WW    56
#define HWS   3136        // H*W
#define NPOS  6272        // B*H*W
#define HEADS 4
#define HD    32

using f32x4 = __attribute__((ext_vector_type(4))) float;
using s16x8 = __attribute__((ext_vector_type(8))) short;

// fp32 -> bf16 round-to-nearest-even
__device__ __forceinline__ unsigned short f2bf(float f) {
  unsigned u = __builtin_bit_cast(unsigned, f);
  u += 0x7FFFu + ((u >> 16) & 1u);
  return (unsigned short)(u >> 16);
}
__device__ __forceinline__ unsigned pack2bf(float a, float b) {
  return (unsigned)f2bf(a) | ((unsigned)f2bf(b) << 16);
}
// 4 packed bf16 (uint2) -> float4
__device__ __forceinline__ float4 bf4tof(uint2 u) {
  float4 r;
  r.x = __builtin_bit_cast(float, u.x << 16);
  r.y = __builtin_bit_cast(float, u.x & 0xFFFF0000u);
  r.z = __builtin_bit_cast(float, u.y << 16);
  r.w = __builtin_bit_cast(float, u.y & 0xFFFF0000u);
  return r;
}

// ---------------------------------------------------------------------------
// LN1: x (NCHW fp32) -> xn (N x C, bf16)   [R7-verified]
// ---------------------------------------------------------------------------
__global__ __launch_bounds__(256) void ln1_kernel(const float* __restrict__ x,
                                                  const float* __restrict__ g,
                                                  const float* __restrict__ be,
                                                  unsigned short* __restrict__ out) {
  __shared__ float tile[128 * 65];
  __shared__ float mu_s[64];
  __shared__ float rs_s[64];
  const int p0 = blockIdx.x * 64;
  const int b  = (p0 >= HWS) ? 1 : 0;
  const int s0 = p0 - b * HWS;
  const int tid = threadIdx.x;

  for (int idx = tid; idx < 8192; idx += 256) {
    int c = idx >> 6, p = idx & 63;
    tile[c * 65 + p] = x[(size_t)(b * CH + c) * HWS + s0 + p];
  }
  __syncthreads();
  {
    int p = tid >> 2, q = tid & 3;
    float sum = 0.f, sq = 0.f;
#pragma unroll
    for (int t = 0; t < 32; ++t) {
      float v = tile[(q * 32 + t) * 65 + p];
      sum += v; sq += v * v;
    }
    sum += __shfl_xor(sum, 1); sq += __shfl_xor(sq, 1);
    sum += __shfl_xor(sum, 2); sq += __shfl_xor(sq, 2);
    float mu  = sum * 0.0078125f;
    float var = sq * 0.0078125f - mu * mu;
    float rs  = rsqrtf(var + 1e-5f);
    if (q == 0) { mu_s[p] = mu; rs_s[p] = rs; }
  }
  __syncthreads();
  for (int idx = tid; idx < 4096; idx += 256) {
    int nl = idx >> 6, c2 = idx & 63;
    int c0 = 2 * c2;
    float v0 = (tile[c0 * 65 + nl] - mu_s[nl]) * rs_s[nl] * g[c0] + be[c0];
    float v1 = (tile[(c0 + 1) * 65 + nl] - mu_s[nl]) * rs_s[nl] * g[c0 + 1] + be[c0 + 1];
    reinterpret_cast<unsigned*>(out)[(size_t)(p0 + nl) * 64 + c2] = pack2bf(v0, v1);
  }
}

// ---------------------------------------------------------------------------
// MFMA tile helpers.  LDS bf16 tiles, byte ^= (row&7)<<4 XOR swizzle.
// 256 threads = 4 waves; wave w -> quadrant (w>>1, w&1); 2x2 16x16x32 frags.
// C/D layout: col = lane&15, row = (lane>>4)*4 + reg.
// ---------------------------------------------------------------------------
__device__ __forceinline__ void stage64(const unsigned short* __restrict__ src,
                                        int stride, int row0, int kc,
                                        int tid, char* dstB) {
#pragma unroll
  for (int c = 0; c < 2; ++c) {
    int lin = c * 256 + tid;          // 0..511
    int row = lin >> 3;               // 0..63
    int k8  = (lin & 7) << 3;         // 0..56
    int byte = (row << 7) + (k8 << 1);
    byte ^= (row & 7) << 4;
    *reinterpret_cast<uint4*>(dstB + byte) =
        *reinterpret_cast<const uint4*>(src + (size_t)(row0 + row) * stride + kc + k8);
  }
}

// Same tile layout, source fp32 converted to bf16 on the fly.  [R8-verified]
__device__ __forceinline__ void stage64_f32(const float* __restrict__ src,
                                            int stride, int row0, int kc,
                                            int tid, char* dstB) {
#pragma unroll
  for (int c = 0; c < 2; ++c) {
    int lin = c * 256 + tid;
    int row = lin >> 3;
    int k8  = (lin & 7) << 3;
    int byte = (row << 7) + (k8 << 1);
    byte ^= (row & 7) << 4;
    const float* s = src + (size_t)(row0 + row) * stride + kc + k8;
    float4 va = *reinterpret_cast<const float4*>(s);
    float4 vb = *reinterpret_cast<const float4*>(s + 4);
    uint4 o;
    o.x = pack2bf(va.x, va.y);
    o.y = pack2bf(va.z, va.w);
    o.z = pack2bf(vb.x, vb.y);
    o.w = pack2bf(vb.z, vb.w);
    *reinterpret_cast<uint4*>(dstB + byte) = o;
  }
}

// aStrideB: bytes per A-row in LDS; aKoffB: byte offset of this K-chunk in A row
__device__ __forceinline__ void tile_compute(const char* AsB, int aStrideB, int aKoffB,
                                             const char* WsB, int lane, int wr, int wc,
                                             f32x4 (&acc)[2][2]) {
  const int r_lo = lane & 15, kg = lane >> 4;
#pragma unroll
  for (int ks = 0; ks < 2; ++ks) {
    const int koffW = ks * 64 + kg * 16;
    const int koffA = aKoffB + koffW;
    s16x8 a[2], bf[2];
#pragma unroll
    for (int fi = 0; fi < 2; ++fi) {
      int row = wr * 32 + fi * 16 + r_lo;
      int byte = row * aStrideB + koffA; byte ^= (row & 7) << 4;
      a[fi] = *reinterpret_cast<const s16x8*>(AsB + byte);
    }
#pragma unroll
    for (int ci = 0; ci < 2; ++ci) {
      int row = wc * 32 + ci * 16 + r_lo;
      int byte = (row << 7) + koffW; byte ^= (row & 7) << 4;
      bf[ci] = *reinterpret_cast<const s16x8*>(WsB + byte);
    }
#pragma unroll
    for (int fi = 0; fi < 2; ++fi)
#pragma unroll
      for (int ci = 0; ci < 2; ++ci)
        acc[fi][ci] = __builtin_amdgcn_mfma_f32_16x16x32_bf16(a[fi], bf[ci], acc[fi][ci], 0, 0, 0);
  }
}

__device__ __forceinline__ float gelu_exact(float v) {
  return 0.5f * v * (1.0f + erff(v * 0.70710678118654752f));
}

// ---------------------------------------------------------------------------
// Fused qkv GEMM (both branches).  A = xn (N x 128 bf16), W fp32 on the fly.
// grid (98, 12).  out bf16 N x 384.
// ---------------------------------------------------------------------------
__global__ __launch_bounds__(256) void qkv_mfma(const unsigned short* __restrict__ A,
                                                const float* __restrict__ W1f,
                                                const float* __restrict__ b1,
                                                unsigned short* __restrict__ o1,
                                                const float* __restrict__ W2f,
                                                const float* __restrict__ b2,
                                                unsigned short* __restrict__ o2) {
  __shared__ char AsB[8192];
  __shared__ char WsB[8192];
  const int tid = threadIdx.x;
  const int lane = tid & 63, w = tid >> 6, wr = w >> 1, wc = w & 1;
  const int p0 = blockIdx.x * 64;
  const int yy = blockIdx.y;
  const bool first = yy < 6;
  const float* Wf = first ? W1f : W2f;
  const float* bias = first ? b1 : b2;
  unsigned short* outp = first ? o1 : o2;
  const int n0 = (first ? yy : yy - 6) * 64;

  f32x4 acc[2][2];
#pragma unroll
  for (int i = 0; i < 2; ++i)
#pragma unroll
    for (int j = 0; j < 2; ++j) acc[i][j] = (f32x4){0.f, 0.f, 0.f, 0.f};

  for (int kc = 0; kc < 128; kc += 64) {
    if (kc) __syncthreads();
    stage64(A, 128, p0, kc, tid, AsB);
    stage64_f32(Wf, 128, n0, kc, tid, WsB);
    __syncthreads();
    tile_compute(AsB, 128, 0, WsB, lane, wr, wc, acc);
  }
  const int r_lo = lane & 15, kg = lane >> 4;
#pragma unroll
  for (int ci = 0; ci < 2; ++ci) {
    int col = n0 + wc * 32 + ci * 16 + r_lo;
    float bc = bias[col];
#pragma unroll
    for (int fi = 0; fi < 2; ++fi) {
      int row0 = p0 + wr * 32 + fi * 16 + kg * 4;
#pragma unroll
      for (int r = 0; r < 4; ++r)
        outp[(size_t)(row0 + r) * 384 + col] = f2bf(acc[fi][ci][r] + bc);
    }
  }
}

// ---------------------------------------------------------------------------
// x2 (N x C fp32) = x(NCHW res) + attn1@W1^T + b1 + attn2@W2^T + b2
// ---------------------------------------------------------------------------
__global__ __launch_bounds__(256) void proj_mfma(const unsigned short* __restrict__ A1,
                                                 const float* __restrict__ W1f,
                                                 const float* __restrict__ b1,
                                                 const unsigned short* __restrict__ A2,
                                                 const float* __restrict__ W2f,
                                                 const float* __restrict__ b2,
                                                 const float* __restrict__ xres,
                                                 float* __restrict__ x2out) {
  __shared__ char AsB[8192];
  __shared__ char WsB[8192];
  const int tid = threadIdx.x;
  const int lane = tid & 63, w = tid >> 6, wr = w >> 1, wc = w & 1;
  const int p0 = blockIdx.x * 64, n0 = blockIdx.y * 64;
  const int bb = (p0 >= HWS) ? 1 : 0;
  const int s0 = p0 - bb * HWS;
  f32x4 acc[2][2];
#pragma unroll
  for (int i = 0; i < 2; ++i)
#pragma unroll
    for (int j = 0; j < 2; ++j) acc[i][j] = (f32x4){0.f, 0.f, 0.f, 0.f};

  const unsigned short* Ap[2] = {A1, A2};
  const float* Wp[2] = {W1f, W2f};
#pragma unroll
  for (int s2 = 0; s2 < 2; ++s2) {
    for (int kc = 0; kc < 128; kc += 64) {
      if (s2 || kc) __syncthreads();
      stage64(Ap[s2], 128, p0, kc, tid, AsB);
      stage64_f32(Wp[s2], 128, n0, kc, tid, WsB);
      __syncthreads();
      tile_compute(AsB, 128, 0, WsB, lane, wr, wc, acc);
    }
  }
  const int r_lo = lane & 15, kg = lane >> 4;
#pragma unroll
  for (int ci = 0; ci < 2; ++ci) {
    int col = n0 + wc * 32 + ci * 16 + r_lo;
    float bc = b1[col] + b2[col];
#pragma unroll
    for (int fi = 0; fi < 2; ++fi) {
      int rloc = wr * 32 + fi * 16 + kg * 4;
      float4 xr = *reinterpret_cast<const float4*>(
          &xres[(size_t)(bb * CH + col) * HWS + s0 + rloc]);
      int row0 = p0 + rloc;
      x2out[(size_t)(row0 + 0) * CH + col] = acc[fi][ci][0] + bc + xr.x;
      x2out[(size_t)(row0 + 1) * CH + col] = acc[fi][ci][1] + bc + xr.y;
      x2out[(size_t)(row0 + 2) * CH + col] = acc[fi][ci][2] + bc + xr.z;
      x2out[(size_t)(row0 + 3) * CH + col] = acc[fi][ci][3] + bc + xr.w;
    }
  }
}

// ---------------------------------------------------------------------------
// fc1 with fused LN2: A = LN(x2) computed in-kernel into LDS (bf16, swizzled).
// out = gelu(A @ fc1_w^T + b) bf16, N x 256.  grid (98, 4).
// ---------------------------------------------------------------------------
__global__ __launch_bounds__(256) void fc1ln_mfma(const float* __restrict__ x2,
                                                  const float* __restrict__ g,
                                                  const float* __restrict__ be,
                                                  const float* __restrict__ Wf,
                                                  const float* __restrict__ bias,
                                                  unsigned short* __restrict__ out) {
  __shared__ char AsB[16384];   // 64 rows x 128 k bf16 (256 B/row), swizzled
  __shared__ char WsB[8192];
  const int tid = threadIdx.x;
  const int lane = tid & 63, w = tid >> 6, wr = w >> 1, wc = w & 1;
  const int p0 = blockIdx.x * 64, n0 = blockIdx.y * 64;
  // --- LN2 into AsB: 4 threads per row ---
  {
    const int p = tid >> 2, q = tid & 3;
    const float* row = x2 + (size_t)(p0 + p) * CH + q * 32;
    float4 v[8];
    float sum = 0.f, sq = 0.f;
#pragma unroll
    for (int t = 0; t < 8; ++t) {
      v[t] = *reinterpret_cast<const float4*>(row + t * 4);
      sum += v[t].x + v[t].y + v[t].z + v[t].w;
      sq  += v[t].x * v[t].x + v[t].y * v[t].y + v[t].z * v[t].z + v[t].w * v[t].w;
    }
    sum += __shfl_xor(sum, 1); sq += __shfl_xor(sq, 1);
    sum += __shfl_xor(sum, 2); sq += __shfl_xor(sq, 2);
    float mu = sum * 0.0078125f;
    float rs = rsqrtf(sq * 0.0078125f - mu * mu + 1e-5f);
#pragma unroll
    for (int t = 0; t < 8; t += 2) {
      int d0 = q * 32 + t * 4;
      float4 g0 = *reinterpret_cast<const float4*>(g + d0);
      float4 g1 = *reinterpret_cast<const float4*>(g + d0 + 4);
      float4 b0 = *reinterpret_cast<const float4*>(be + d0);
      float4 b1v = *reinterpret_cast<const float4*>(be + d0 + 4);
      uint4 o;
      o.x = pack2bf((v[t].x - mu) * rs * g0.x + b0.x, (v[t].y - mu) * rs * g0.y + b0.y);
      o.y = pack2bf((v[t].z - mu) * rs * g0.z + b0.z, (v[t].w - mu) * rs * g0.w + b0.w);
      o.z = pack2bf((v[t+1].x - mu) * rs * g1.x + b1v.x, (v[t+1].y - mu) * rs * g1.y + b1v.y);
      o.w = pack2bf((v[t+1].z - mu) * rs * g1.z + b1v.z, (v[t+1].w - mu) * rs * g1.w + b1v.w);
      int byte = p * 256 + q * 64 + (t >> 1) * 16;
      byte ^= (p & 7) << 4;
      *reinterpret_cast<uint4*>(AsB + byte) = o;
    }
  }
  f32x4 acc[2][2];
#pragma unroll
  for (int i = 0; i < 2; ++i)
#pragma unroll
    for (int j = 0; j < 2; ++j) acc[i][j] = (f32x4){0.f, 0.f, 0.f, 0.f};

  for (int kc = 0; kc < 128; kc += 64) {
    __syncthreads();                       // covers LN writes (kc=0) / prior reads
    stage64_f32(Wf, 128, n0, kc, tid, WsB);
    __syncthreads();
    tile_compute(AsB, 256, kc * 2, WsB, lane, wr, wc, acc);
  }
  const int r_lo = lane & 15, kg = lane >> 4;
#pragma unroll
  for (int ci = 0; ci < 2; ++ci) {
    int col = n0 + wc * 32 + ci * 16 + r_lo;
    float bc = bias[col];
#pragma unroll
    for (int fi = 0; fi < 2; ++fi) {
      int row0 = p0 + wr * 32 + fi * 16 + kg * 4;
#pragma unroll
      for (int r = 0; r < 4; ++r)
        out[(size_t)(row0 + r) * 256 + col] = f2bf(gelu_exact(acc[fi][ci][r] + bc));
    }
  }
}

// ---------------------------------------------------------------------------
// d_out (NCHW fp32) = x2 + h @ fc2_w^T + fc2_b ;  K = 256
// ---------------------------------------------------------------------------
__global__ __launch_bounds__(256) void fc2_mfma(const unsigned short* __restrict__ A,
                                                const float* __restrict__ Wf,
                                                const float* __restrict__ bias,
                                                const float* __restrict__ x2,
                                                float* __restrict__ out) {
  __shared__ char AsB[8192];
  __shared__ char WsB[8192];
  const int tid = threadIdx.x;
  const int lane = tid & 63, w = tid >> 6, wr = w >> 1, wc = w & 1;
  const int p0 = blockIdx.x * 64, n0 = blockIdx.y * 64;
  const int bb = (p0 >= HWS) ? 1 : 0;
  const int s0 = p0 - bb * HWS;
  f32x4 acc[2][2];
#pragma unroll
  for (int i = 0; i < 2; ++i)
#pragma unroll
    for (int j = 0; j < 2; ++j) acc[i][j] = (f32x4){0.f, 0.f, 0.f, 0.f};

  for (int kc = 0; kc < 256; kc += 64) {
    if (kc) __syncthreads();
    stage64(A, 256, p0, kc, tid, AsB);
    stage64_f32(Wf, 256, n0, kc, tid, WsB);
    __syncthreads();
    tile_compute(AsB, 128, 0, WsB, lane, wr, wc, acc);
  }
  const int r_lo = lane & 15, kg = lane >> 4;
#pragma unroll
  for (int ci = 0; ci < 2; ++ci) {
    int col = n0 + wc * 32 + ci * 16 + r_lo;
    float bc = bias[col];
#pragma unroll
    for (int fi = 0; fi < 2; ++fi) {
      int rloc = wr * 32 + fi * 16 + kg * 4;
      int row0 = p0 + rloc;
      float4 o;
      o.x = acc[fi][ci][0] + bc + x2[(size_t)(row0 + 0) * CH + col];
      o.y = acc[fi][ci][1] + bc + x2[(size_t)(row0 + 1) * CH + col];
      o.z = acc[fi][ci][2] + bc + x2[(size_t)(row0 + 2) * CH + col];
      o.w = acc[fi][ci][3] + bc + x2[(size_t)(row0 + 3) * CH + col];
      *reinterpret_cast<float4*>(&out[(size_t)(bb * CH + col) * HWS + s0 + rloc]) = o;
    }
  }
}

// ---------------------------------------------------------------------------
// Neighborhood attention, 4 lanes x 8 channels per output (uint4 16B loads,
// 2-step shuffle reduce, 16 outputs/wave).  qkv bf16 N x 384, out bf16 N x 128.
// ---------------------------------------------------------------------------
template <int NW>
__device__ __forceinline__ void natten_body(const unsigned short* __restrict__ qkvb,
                                            const float* __restrict__ rpb,
                                            unsigned short* __restrict__ out,
                                            int blk, int tid) {
  const int g   = blk * 64 + (tid >> 2);   // output index: ((b*4+h)*56+i)*56+j
  const int sub = tid & 3;                 // 8-channel slice
  const int j  = g % WW;
  const int t1 = g / WW;
  const int i  = t1 % HH;
  const int t2 = t1 / HH;
  const int h  = t2 & 3;
  const int b  = t2 >> 2;
  const int n  = b * HWS + i * WW + j;

  const float scale = 0.17677669529663687f;  // 1/sqrt(32)
  uint4 qu = *reinterpret_cast<const uint4*>(qkvb + (size_t)n * 384 + h * 32 + sub * 8);
  float4 qa = bf4tof(make_uint2(qu.x, qu.y));
  float4 qb = bf4tof(make_uint2(qu.z, qu.w));
  qa.x *= scale; qa.y *= scale; qa.z *= scale; qa.w *= scale;
  qb.x *= scale; qb.y *= scale; qb.z *= scale; qb.w *= scale;

  const int si = min(max(i - NW / 2, 0), HH - NW);
  const int sj = min(max(j - NW / 2, 0), WW - NW);
  const float* rb = rpb + h * (2 * NW - 1) * (2 * NW - 1)
                    + (NW - 1 - (i - si)) * (2 * NW - 1) + (NW - 1 - (j - sj));
  float sc[NW * NW];
  float mx = -1e30f;
#pragma unroll
  for (int ki = 0; ki < NW; ++ki) {
#pragma unroll
    for (int kj = 0; kj < NW; ++kj) {
      const int nn = b * HWS + (si + ki) * WW + sj + kj;
      uint4 ku = *reinterpret_cast<const uint4*>(
          qkvb + (size_t)nn * 384 + 128 + h * 32 + sub * 8);
      float4 ka = bf4tof(make_uint2(ku.x, ku.y));
      float4 kb = bf4tof(make_uint2(ku.z, ku.w));
      float p = qa.x * ka.x + qa.y * ka.y + qa.z * ka.z + qa.w * ka.w
              + qb.x * kb.x + qb.y * kb.y + qb.z * kb.z + qb.w * kb.w;
      p += __shfl_xor(p, 1);
      p += __shfl_xor(p, 2);
      p += rb[ki * (2 * NW - 1) + kj];
      sc[ki * NW + kj] = p;
      mx = fmaxf(mx, p);
    }
  }
  float ssum = 0.f;
#pragma unroll
  for (int kk = 0; kk < NW * NW; ++kk) {
    sc[kk] = __expf(sc[kk] - mx);
    ssum += sc[kk];
  }
  float4 oa = make_float4(0.f, 0.f, 0.f, 0.f);
  float4 ob = make_float4(0.f, 0.f, 0.f, 0.f);
#pragma unroll
  for (int ki = 0; ki < NW; ++ki) {
#pragma unroll
    for (int kj = 0; kj < NW; ++kj) {
      const int nn = b * HWS + (si + ki) * WW + sj + kj;
      uint4 vu = *reinterpret_cast<const uint4*>(
          qkvb + (size_t)nn * 384 + 256 + h * 32 + sub * 8);
      float4 va = bf4tof(make_uint2(vu.x, vu.y));
      float4 vb = bf4tof(make_uint2(vu.z, vu.w));
      float p = sc[ki * NW + kj];
      oa.x = fmaf(p, va.x, oa.x); oa.y = fmaf(p, va.y, oa.y);
      oa.z = fmaf(p, va.z, oa.z); oa.w = fmaf(p, va.w, oa.w);
      ob.x = fmaf(p, vb.x, ob.x); ob.y = fmaf(p, vb.y, ob.y);
      ob.z = fmaf(p, vb.z, ob.z); ob.w = fmaf(p, vb.w, ob.w);
    }
  }
  float inv = 1.0f / ssum;
  uint4 ov;
  ov.x = pack2bf(oa.x * inv, oa.y * inv);
  ov.y = pack2bf(oa.z * inv, oa.w * inv);
  ov.z = pack2bf(ob.x * inv, ob.y * inv);
  ov.w = pack2bf(ob.z * inv, ob.w * inv);
  *reinterpret_cast<uint4*>(out + (size_t)n * CH + h * 32 + sub * 8) = ov;
}

__global__ __launch_bounds__(256) void natten_fused(const unsigned short* __restrict__ qkv1,
                                                    const float* __restrict__ rpb1,
                                                    unsigned short* __restrict__ a1,
                                                    const unsigned short* __restrict__ qkv2,
                                                    const float* __restrict__ rpb2,
                                                    unsigned short* __restrict__ a2) {
  if (blockIdx.x < 392) natten_body<7>(qkv1, rpb1, a1, blockIdx.x, threadIdx.x);
  else                  natten_body<5>(qkv2, rpb2, a2, blockIdx.x - 392, threadIdx.x);
}

// ---------------------------------------------------------------------------
extern "C" void kernel_launch(void* const* d_in, const int* in_sizes, int n_in,
                              void* d_out, int out_size, void* d_ws, size_t ws_size,
                              hipStream_t stream) {
  const float* x       = (const float*)d_in[0];
  const float* ln1_g   = (const float*)d_in[1];
  const float* ln1_b   = (const float*)d_in[2];
  const float* qkv_w1  = (const float*)d_in[3];
  const float* qkv_b1  = (const float*)d_in[4];
  const float* proj_w1 = (const float*)d_in[5];
  const float* proj_b1 = (const float*)d_in[6];
  const float* rpb1    = (const float*)d_in[7];
  const float* qkv_w2  = (const float*)d_in[8];
  const float* qkv_b2  = (const float*)d_in[9];
  const float* proj_w2 = (const float*)d_in[10];
  const float* proj_b2 = (const float*)d_in[11];
  const float* rpb2    = (const float*)d_in[12];
  const float* ln2_g   = (const float*)d_in[13];
  const float* ln2_b   = (const float*)d_in[14];
  const float* fc1_w   = (const float*)d_in[15];
  const float* fc1_b   = (const float*)d_in[16];
  const float* fc2_w   = (const float*)d_in[17];
  const float* fc2_b   = (const float*)d_in[18];
  float* out = (float*)d_out;

  // workspace carve-up (bytes, all 256B-aligned)
  char* wsb = (char*)d_ws;
  unsigned short* xn    = (unsigned short*)(wsb);              // N*128 bf16 (1,605,632)
  unsigned short* qkv1  = (unsigned short*)(wsb + 1605632);    // N*384 bf16 (4,816,896)
  unsigned short* qkv2  = (unsigned short*)(wsb + 6422528);    // N*384 bf16
  unsigned short* attn1 = (unsigned short*)(wsb + 11239424);   // N*128 bf16
  unsigned short* attn2 = (unsigned short*)(wsb + 12845056);   // N*128 bf16
  float*          x2    = (float*)(wsb + 14450688);            // N*128 f32  (3,211,264)
  unsigned short* hbuf  = (unsigned short*)(wsb + 17661952);   // N*256 bf16 (3,211,264)

  ln1_kernel<<<98, 256, 0, stream>>>(x, ln1_g, ln1_b, xn);
  qkv_mfma<<<dim3(98, 12), 256, 0, stream>>>(xn, qkv_w1, qkv_b1, qkv1,
                                             qkv_w2, qkv_b2, qkv2);
  natten_fused<<<784, 256, 0, stream>>>(qkv1, rpb1, attn1, qkv2, rpb2, attn2);
  proj_mfma<<<dim3(98, 2), 256, 0, stream>>>(attn1, proj_w1, proj_b1,
                                             attn2, proj_w2, proj_b2, x, x2);
  fc1ln_mfma<<<dim3(98, 4), 256, 0, stream>>>(x2, ln2_g, ln2_b, fc1_w, fc1_b, hbuf);
  fc2_mfma<<<dim3(98, 2), 256, 0, stream>>>(hbuf, fc2_w, fc2_b, x2, out);
}

// Round 11
// 158.362 us; speedup vs baseline: 1.1388x; 1.1388x over previous
//
#include <hip/hip_runtime.h>
#include <hip/hip_bf16.h>

// Problem constants (B=2, C=128, H=W=56)
#define BATCH 2
#define CH    128
#define HH    56
#define WW    56
#define HWS   3136        // H*W
#define NPOS  6272        // B*H*W
#define HEADS 4
#define HD    32

using f32x4 = __attribute__((ext_vector_type(4))) float;
using s16x8 = __attribute__((ext_vector_type(8))) short;

// fp32 -> bf16 round-to-nearest-even
__device__ __forceinline__ unsigned short f2bf(float f) {
  unsigned u = __builtin_bit_cast(unsigned, f);
  u += 0x7FFFu + ((u >> 16) & 1u);
  return (unsigned short)(u >> 16);
}
__device__ __forceinline__ unsigned pack2bf(float a, float b) {
  return (unsigned)f2bf(a) | ((unsigned)f2bf(b) << 16);
}
// 4 packed bf16 (uint2) -> float4
__device__ __forceinline__ float4 bf4tof(uint2 u) {
  float4 r;
  r.x = __builtin_bit_cast(float, u.x << 16);
  r.y = __builtin_bit_cast(float, u.x & 0xFFFF0000u);
  r.z = __builtin_bit_cast(float, u.y << 16);
  r.w = __builtin_bit_cast(float, u.y & 0xFFFF0000u);
  return r;
}

// ---------------------------------------------------------------------------
// LN1: x (NCHW fp32) -> xn (N x C, bf16)   [R7-verified]
// ---------------------------------------------------------------------------
__global__ __launch_bounds__(256) void ln1_kernel(const float* __restrict__ x,
                                                  const float* __restrict__ g,
                                                  const float* __restrict__ be,
                                                  unsigned short* __restrict__ out) {
  __shared__ float tile[128 * 65];
  __shared__ float mu_s[64];
  __shared__ float rs_s[64];
  const int p0 = blockIdx.x * 64;
  const int b  = (p0 >= HWS) ? 1 : 0;
  const int s0 = p0 - b * HWS;
  const int tid = threadIdx.x;

  for (int idx = tid; idx < 8192; idx += 256) {
    int c = idx >> 6, p = idx & 63;
    tile[c * 65 + p] = x[(size_t)(b * CH + c) * HWS + s0 + p];
  }
  __syncthreads();
  {
    int p = tid >> 2, q = tid & 3;
    float sum = 0.f, sq = 0.f;
#pragma unroll
    for (int t = 0; t < 32; ++t) {
      float v = tile[(q * 32 + t) * 65 + p];
      sum += v; sq += v * v;
    }
    sum += __shfl_xor(sum, 1); sq += __shfl_xor(sq, 1);
    sum += __shfl_xor(sum, 2); sq += __shfl_xor(sq, 2);
    float mu  = sum * 0.0078125f;
    float var = sq * 0.0078125f - mu * mu;
    float rs  = rsqrtf(var + 1e-5f);
    if (q == 0) { mu_s[p] = mu; rs_s[p] = rs; }
  }
  __syncthreads();
  for (int idx = tid; idx < 4096; idx += 256) {
    int nl = idx >> 6, c2 = idx & 63;
    int c0 = 2 * c2;
    float v0 = (tile[c0 * 65 + nl] - mu_s[nl]) * rs_s[nl] * g[c0] + be[c0];
    float v1 = (tile[(c0 + 1) * 65 + nl] - mu_s[nl]) * rs_s[nl] * g[c0 + 1] + be[c0 + 1];
    reinterpret_cast<unsigned*>(out)[(size_t)(p0 + nl) * 64 + c2] = pack2bf(v0, v1);
  }
}

// ---------------------------------------------------------------------------
// MFMA tile helpers.  LDS bf16 tiles, byte ^= (row&7)<<4 XOR swizzle.
// Generalized to arbitrary K-extent per tile (kElems = 64/128/256).
// 256 threads = 4 waves; wave w -> quadrant (w>>1, w&1); 2x2 16x16x32 frags.
// C/D layout: col = lane&15, row = (lane>>4)*4 + reg.
// ---------------------------------------------------------------------------
__device__ __forceinline__ void stage_tile(const unsigned short* __restrict__ src,
                                           int stride, int row0, int kElems,
                                           int tid, char* dstB) {
  const int upr = kElems >> 3;            // 16B units per row
  const int total = 64 * upr;
#pragma unroll
  for (int u = tid; u < total; u += 256) {
    int row = u / upr;
    int ku  = u % upr;
    int byte = row * (kElems << 1) + (ku << 4);
    byte ^= (row & 7) << 4;
    *reinterpret_cast<uint4*>(dstB + byte) =
        *reinterpret_cast<const uint4*>(src + (size_t)(row0 + row) * stride + (ku << 3));
  }
}

// fp32 source, converted to bf16 on the fly.  [R8-verified conversion]
__device__ __forceinline__ void stage_tile_f32(const float* __restrict__ src,
                                               int stride, int row0, int kElems,
                                               int tid, char* dstB) {
  const int upr = kElems >> 3;
  const int total = 64 * upr;
#pragma unroll
  for (int u = tid; u < total; u += 256) {
    int row = u / upr;
    int ku  = u % upr;
    int byte = row * (kElems << 1) + (ku << 4);
    byte ^= (row & 7) << 4;
    const float* s = src + (size_t)(row0 + row) * stride + (ku << 3);
    float4 va = *reinterpret_cast<const float4*>(s);
    float4 vb = *reinterpret_cast<const float4*>(s + 4);
    uint4 o;
    o.x = pack2bf(va.x, va.y);
    o.y = pack2bf(va.z, va.w);
    o.z = pack2bf(vb.x, vb.y);
    o.w = pack2bf(vb.z, vb.w);
    *reinterpret_cast<uint4*>(dstB + byte) = o;
  }
}

// One K=64 slab: A rows at aStrideB bytes (+aKoffB), W rows at wStrideB (+wKoffB).
__device__ __forceinline__ void tile_compute2(const char* AsB, int aStrideB, int aKoffB,
                                              const char* WsB, int wStrideB, int wKoffB,
                                              int lane, int wr, int wc,
                                              f32x4 (&acc)[2][2]) {
  const int r_lo = lane & 15, kg = lane >> 4;
#pragma unroll
  for (int ks = 0; ks < 2; ++ks) {
    const int ko = ks * 64 + kg * 16;
    const int koffA = aKoffB + ko;
    const int koffW = wKoffB + ko;
    s16x8 a[2], bf[2];
#pragma unroll
    for (int fi = 0; fi < 2; ++fi) {
      int row = wr * 32 + fi * 16 + r_lo;
      int byte = row * aStrideB + koffA; byte ^= (row & 7) << 4;
      a[fi] = *reinterpret_cast<const s16x8*>(AsB + byte);
    }
#pragma unroll
    for (int ci = 0; ci < 2; ++ci) {
      int row = wc * 32 + ci * 16 + r_lo;
      int byte = row * wStrideB + koffW; byte ^= (row & 7) << 4;
      bf[ci] = *reinterpret_cast<const s16x8*>(WsB + byte);
    }
#pragma unroll
    for (int fi = 0; fi < 2; ++fi)
#pragma unroll
      for (int ci = 0; ci < 2; ++ci)
        acc[fi][ci] = __builtin_amdgcn_mfma_f32_16x16x32_bf16(a[fi], bf[ci], acc[fi][ci], 0, 0, 0);
  }
}

__device__ __forceinline__ float gelu_exact(float v) {
  return 0.5f * v * (1.0f + erff(v * 0.70710678118654752f));
}

// ---------------------------------------------------------------------------
// Fused qkv GEMM (both branches).  A = xn (N x 128 bf16), W fp32 on the fly.
// Single-shot stage (A 16KB + W 16KB), ONE barrier.  grid (98, 12).
// ---------------------------------------------------------------------------
__global__ __launch_bounds__(256) void qkv_mfma(const unsigned short* __restrict__ A,
                                                const float* __restrict__ W1f,
                                                const float* __restrict__ b1,
                                                unsigned short* __restrict__ o1,
                                                const float* __restrict__ W2f,
                                                const float* __restrict__ b2,
                                                unsigned short* __restrict__ o2) {
  __shared__ char AsB[16384];   // 64 x 128k bf16, 256B rows
  __shared__ char WsB[16384];
  const int tid = threadIdx.x;
  const int lane = tid & 63, w = tid >> 6, wr = w >> 1, wc = w & 1;
  const int p0 = blockIdx.x * 64;
  const int yy = blockIdx.y;
  const bool first = yy < 6;
  const float* Wf = first ? W1f : W2f;
  const float* bias = first ? b1 : b2;
  unsigned short* outp = first ? o1 : o2;
  const int n0 = (first ? yy : yy - 6) * 64;

  stage_tile(A, 128, p0, 128, tid, AsB);
  stage_tile_f32(Wf, 128, n0, 128, tid, WsB);

  f32x4 acc[2][2];
#pragma unroll
  for (int i = 0; i < 2; ++i)
#pragma unroll
    for (int j = 0; j < 2; ++j) acc[i][j] = (f32x4){0.f, 0.f, 0.f, 0.f};

  __syncthreads();
  tile_compute2(AsB, 256, 0,   WsB, 256, 0,   lane, wr, wc, acc);
  tile_compute2(AsB, 256, 128, WsB, 256, 128, lane, wr, wc, acc);

  const int r_lo = lane & 15, kg = lane >> 4;
#pragma unroll
  for (int ci = 0; ci < 2; ++ci) {
    int col = n0 + wc * 32 + ci * 16 + r_lo;
    float bc = bias[col];
#pragma unroll
    for (int fi = 0; fi < 2; ++fi) {
      int row0 = p0 + wr * 32 + fi * 16 + kg * 4;
#pragma unroll
      for (int r = 0; r < 4; ++r)
        outp[(size_t)(row0 + r) * 384 + col] = f2bf(acc[fi][ci][r] + bc);
    }
  }
}

// ---------------------------------------------------------------------------
// x2 (N x C fp32) = x(NCHW res) + attn1@W1^T + b1 + attn2@W2^T + b2
// Single-shot stage of BOTH branches (64KB LDS; grid 196 blocks -> <1/CU,
// occupancy unaffected).  ONE barrier.
// ---------------------------------------------------------------------------
__global__ __launch_bounds__(256) void proj_mfma(const unsigned short* __restrict__ A1,
                                                 const float* __restrict__ W1f,
                                                 const float* __restrict__ b1,
                                                 const unsigned short* __restrict__ A2,
                                                 const float* __restrict__ W2f,
                                                 const float* __restrict__ b2,
                                                 const float* __restrict__ xres,
                                                 float* __restrict__ x2out) {
  __shared__ char A1B[16384];
  __shared__ char W1B[16384];
  __shared__ char A2B[16384];
  __shared__ char W2B[16384];
  const int tid = threadIdx.x;
  const int lane = tid & 63, w = tid >> 6, wr = w >> 1, wc = w & 1;
  const int p0 = blockIdx.x * 64, n0 = blockIdx.y * 64;
  const int bb = (p0 >= HWS) ? 1 : 0;
  const int s0 = p0 - bb * HWS;

  stage_tile(A1, 128, p0, 128, tid, A1B);
  stage_tile_f32(W1f, 128, n0, 128, tid, W1B);
  stage_tile(A2, 128, p0, 128, tid, A2B);
  stage_tile_f32(W2f, 128, n0, 128, tid, W2B);

  f32x4 acc[2][2];
#pragma unroll
  for (int i = 0; i < 2; ++i)
#pragma unroll
    for (int j = 0; j < 2; ++j) acc[i][j] = (f32x4){0.f, 0.f, 0.f, 0.f};

  __syncthreads();
  tile_compute2(A1B, 256, 0,   W1B, 256, 0,   lane, wr, wc, acc);
  tile_compute2(A1B, 256, 128, W1B, 256, 128, lane, wr, wc, acc);
  tile_compute2(A2B, 256, 0,   W2B, 256, 0,   lane, wr, wc, acc);
  tile_compute2(A2B, 256, 128, W2B, 256, 128, lane, wr, wc, acc);

  const int r_lo = lane & 15, kg = lane >> 4;
#pragma unroll
  for (int ci = 0; ci < 2; ++ci) {
    int col = n0 + wc * 32 + ci * 16 + r_lo;
    float bc = b1[col] + b2[col];
#pragma unroll
    for (int fi = 0; fi < 2; ++fi) {
      int rloc = wr * 32 + fi * 16 + kg * 4;
      float4 xr = *reinterpret_cast<const float4*>(
          &xres[(size_t)(bb * CH + col) * HWS + s0 + rloc]);
      int row0 = p0 + rloc;
      x2out[(size_t)(row0 + 0) * CH + col] = acc[fi][ci][0] + bc + xr.x;
      x2out[(size_t)(row0 + 1) * CH + col] = acc[fi][ci][1] + bc + xr.y;
      x2out[(size_t)(row0 + 2) * CH + col] = acc[fi][ci][2] + bc + xr.z;
      x2out[(size_t)(row0 + 3) * CH + col] = acc[fi][ci][3] + bc + xr.w;
    }
  }
}

// ---------------------------------------------------------------------------
// fc1 with fused LN2: A = LN(x2) built into LDS (bf16, swizzled), W staged
// full-K.  ONE barrier.  grid (98, 4).
// ---------------------------------------------------------------------------
__global__ __launch_bounds__(256) void fc1ln_mfma(const float* __restrict__ x2,
                                                  const float* __restrict__ g,
                                                  const float* __restrict__ be,
                                                  const float* __restrict__ Wf,
                                                  const float* __restrict__ bias,
                                                  unsigned short* __restrict__ out) {
  __shared__ char AsB[16384];   // 64 rows x 128 k bf16 (256 B/row), swizzled
  __shared__ char WsB[16384];
  const int tid = threadIdx.x;
  const int lane = tid & 63, w = tid >> 6, wr = w >> 1, wc = w & 1;
  const int p0 = blockIdx.x * 64, n0 = blockIdx.y * 64;
  // --- LN2 into AsB: 4 threads per row ---
  {
    const int p = tid >> 2, q = tid & 3;
    const float* row = x2 + (size_t)(p0 + p) * CH + q * 32;
    float4 v[8];
    float sum = 0.f, sq = 0.f;
#pragma unroll
    for (int t = 0; t < 8; ++t) {
      v[t] = *reinterpret_cast<const float4*>(row + t * 4);
      sum += v[t].x + v[t].y + v[t].z + v[t].w;
      sq  += v[t].x * v[t].x + v[t].y * v[t].y + v[t].z * v[t].z + v[t].w * v[t].w;
    }
    sum += __shfl_xor(sum, 1); sq += __shfl_xor(sq, 1);
    sum += __shfl_xor(sum, 2); sq += __shfl_xor(sq, 2);
    float mu = sum * 0.0078125f;
    float rs = rsqrtf(sq * 0.0078125f - mu * mu + 1e-5f);
#pragma unroll
    for (int t = 0; t < 8; t += 2) {
      int d0 = q * 32 + t * 4;
      float4 g0 = *reinterpret_cast<const float4*>(g + d0);
      float4 g1 = *reinterpret_cast<const float4*>(g + d0 + 4);
      float4 b0 = *reinterpret_cast<const float4*>(be + d0);
      float4 b1v = *reinterpret_cast<const float4*>(be + d0 + 4);
      uint4 o;
      o.x = pack2bf((v[t].x - mu) * rs * g0.x + b0.x, (v[t].y - mu) * rs * g0.y + b0.y);
      o.y = pack2bf((v[t].z - mu) * rs * g0.z + b0.z, (v[t].w - mu) * rs * g0.w + b0.w);
      o.z = pack2bf((v[t+1].x - mu) * rs * g1.x + b1v.x, (v[t+1].y - mu) * rs * g1.y + b1v.y);
      o.w = pack2bf((v[t+1].z - mu) * rs * g1.z + b1v.z, (v[t+1].w - mu) * rs * g1.w + b1v.w);
      int byte = p * 256 + q * 64 + (t >> 1) * 16;
      byte ^= (p & 7) << 4;
      *reinterpret_cast<uint4*>(AsB + byte) = o;
    }
  }
  stage_tile_f32(Wf, 128, n0, 128, tid, WsB);

  f32x4 acc[2][2];
#pragma unroll
  for (int i = 0; i < 2; ++i)
#pragma unroll
    for (int j = 0; j < 2; ++j) acc[i][j] = (f32x4){0.f, 0.f, 0.f, 0.f};

  __syncthreads();
  tile_compute2(AsB, 256, 0,   WsB, 256, 0,   lane, wr, wc, acc);
  tile_compute2(AsB, 256, 128, WsB, 256, 128, lane, wr, wc, acc);

  const int r_lo = lane & 15, kg = lane >> 4;
#pragma unroll
  for (int ci = 0; ci < 2; ++ci) {
    int col = n0 + wc * 32 + ci * 16 + r_lo;
    float bc = bias[col];
#pragma unroll
    for (int fi = 0; fi < 2; ++fi) {
      int row0 = p0 + wr * 32 + fi * 16 + kg * 4;
#pragma unroll
      for (int r = 0; r < 4; ++r)
        out[(size_t)(row0 + r) * 256 + col] = f2bf(gelu_exact(acc[fi][ci][r] + bc));
    }
  }
}

// ---------------------------------------------------------------------------
// d_out (NCHW fp32) = x2 + h @ fc2_w^T + fc2_b ;  K = 256.
// Single-shot stage (A 32KB + W 32KB); grid 196 blocks -> occupancy grid-bound
// anyway.  ONE barrier.
// ---------------------------------------------------------------------------
__global__ __launch_bounds__(256) void fc2_mfma(const unsigned short* __restrict__ A,
                                                const float* __restrict__ Wf,
                                                const float* __restrict__ bias,
                                                const float* __restrict__ x2,
                                                float* __restrict__ out) {
  __shared__ char AsB[32768];   // 64 x 256k bf16, 512B rows
  __shared__ char WsB[32768];
  const int tid = threadIdx.x;
  const int lane = tid & 63, w = tid >> 6, wr = w >> 1, wc = w & 1;
  const int p0 = blockIdx.x * 64, n0 = blockIdx.y * 64;
  const int bb = (p0 >= HWS) ? 1 : 0;
  const int s0 = p0 - bb * HWS;

  stage_tile(A, 256, p0, 256, tid, AsB);
  stage_tile_f32(Wf, 256, n0, 256, tid, WsB);

  f32x4 acc[2][2];
#pragma unroll
  for (int i = 0; i < 2; ++i)
#pragma unroll
    for (int j = 0; j < 2; ++j) acc[i][j] = (f32x4){0.f, 0.f, 0.f, 0.f};

  __syncthreads();
#pragma unroll
  for (int kb = 0; kb < 4; ++kb)
    tile_compute2(AsB, 512, kb * 128, WsB, 512, kb * 128, lane, wr, wc, acc);

  const int r_lo = lane & 15, kg = lane >> 4;
#pragma unroll
  for (int ci = 0; ci < 2; ++ci) {
    int col = n0 + wc * 32 + ci * 16 + r_lo;
    float bc = bias[col];
#pragma unroll
    for (int fi = 0; fi < 2; ++fi) {
      int rloc = wr * 32 + fi * 16 + kg * 4;
      int row0 = p0 + rloc;
      float4 o;
      o.x = acc[fi][ci][0] + bc + x2[(size_t)(row0 + 0) * CH + col];
      o.y = acc[fi][ci][1] + bc + x2[(size_t)(row0 + 1) * CH + col];
      o.z = acc[fi][ci][2] + bc + x2[(size_t)(row0 + 2) * CH + col];
      o.w = acc[fi][ci][3] + bc + x2[(size_t)(row0 + 3) * CH + col];
      *reinterpret_cast<float4*>(&out[(size_t)(bb * CH + col) * HWS + s0 + rloc]) = o;
    }
  }
}

// ---------------------------------------------------------------------------
// Neighborhood attention (both windows in one launch), 8 lanes per output.
// qkv bf16: N x 384.  out bf16 N x 128.   [R9-verified fastest variant]
// ---------------------------------------------------------------------------
template <int NW>
__device__ __forceinline__ void natten_body(const unsigned short* __restrict__ qkvb,
                                            const float* __restrict__ rpb,
                                            unsigned short* __restrict__ out,
                                            int blk, int tid) {
  const int g   = blk * 32 + (tid >> 3);
  const int sub = tid & 7;
  const int j  = g % WW;
  const int t1 = g / WW;
  const int i  = t1 % HH;
  const int t2 = t1 / HH;
  const int h  = t2 & 3;
  const int b  = t2 >> 2;
  const int n  = b * HWS + i * WW + j;

  const float scale = 0.17677669529663687f;  // 1/sqrt(32)
  float4 q = bf4tof(*reinterpret_cast<const uint2*>(qkvb + (size_t)n * 384 + h * 32 + sub * 4));
  q.x *= scale; q.y *= scale; q.z *= scale; q.w *= scale;

  const int si = min(max(i - NW / 2, 0), HH - NW);
  const int sj = min(max(j - NW / 2, 0), WW - NW);
  const float* rb = rpb + h * (2 * NW - 1) * (2 * NW - 1)
                    + (NW - 1 - (i - si)) * (2 * NW - 1) + (NW - 1 - (j - sj));
  float sc[NW * NW];
  float mx = -1e30f;
#pragma unroll
  for (int ki = 0; ki < NW; ++ki) {
#pragma unroll
    for (int kj = 0; kj < NW; ++kj) {
      const int nn = b * HWS + (si + ki) * WW + sj + kj;
      float4 k4 = bf4tof(*reinterpret_cast<const uint2*>(
          qkvb + (size_t)nn * 384 + 128 + h * 32 + sub * 4));
      float p = q.x * k4.x + q.y * k4.y + q.z * k4.z + q.w * k4.w;
      p += __shfl_xor(p, 1);
      p += __shfl_xor(p, 2);
      p += __shfl_xor(p, 4);
      p += rb[ki * (2 * NW - 1) + kj];
      sc[ki * NW + kj] = p;
      mx = fmaxf(mx, p);
    }
  }
  float ssum = 0.f;
#pragma unroll
  for (int kk = 0; kk < NW * NW; ++kk) {
    sc[kk] = __expf(sc[kk] - mx);
    ssum += sc[kk];
  }
  float4 o = make_float4(0.f, 0.f, 0.f, 0.f);
#pragma unroll
  for (int ki = 0; ki < NW; ++ki) {
#pragma unroll
    for (int kj = 0; kj < NW; ++kj) {
      const int nn = b * HWS + (si + ki) * WW + sj + kj;
      float4 v4 = bf4tof(*reinterpret_cast<const uint2*>(
          qkvb + (size_t)nn * 384 + 256 + h * 32 + sub * 4));
      float p = sc[ki * NW + kj];
      o.x = fmaf(p, v4.x, o.x);
      o.y = fmaf(p, v4.y, o.y);
      o.z = fmaf(p, v4.z, o.z);
      o.w = fmaf(p, v4.w, o.w);
    }
  }
  float inv = 1.0f / ssum;
  uint2 ov;
  ov.x = pack2bf(o.x * inv, o.y * inv);
  ov.y = pack2bf(o.z * inv, o.w * inv);
  *reinterpret_cast<uint2*>(out + (size_t)n * CH + h * 32 + sub * 4) = ov;
}

__global__ __launch_bounds__(256) void natten_fused(const unsigned short* __restrict__ qkv1,
                                                    const float* __restrict__ rpb1,
                                                    unsigned short* __restrict__ a1,
                                                    const unsigned short* __restrict__ qkv2,
                                                    const float* __restrict__ rpb2,
                                                    unsigned short* __restrict__ a2) {
  if (blockIdx.x < 784) natten_body<7>(qkv1, rpb1, a1, blockIdx.x, threadIdx.x);
  else                  natten_body<5>(qkv2, rpb2, a2, blockIdx.x - 784, threadIdx.x);
}

// ---------------------------------------------------------------------------
extern "C" void kernel_launch(void* const* d_in, const int* in_sizes, int n_in,
                              void* d_out, int out_size, void* d_ws, size_t ws_size,
                              hipStream_t stream) {
  const float* x       = (const float*)d_in[0];
  const float* ln1_g   = (const float*)d_in[1];
  const float* ln1_b   = (const float*)d_in[2];
  const float* qkv_w1  = (const float*)d_in[3];
  const float* qkv_b1  = (const float*)d_in[4];
  const float* proj_w1 = (const float*)d_in[5];
  const float* proj_b1 = (const float*)d_in[6];
  const float* rpb1    = (const float*)d_in[7];
  const float* qkv_w2  = (const float*)d_in[8];
  const float* qkv_b2  = (const float*)d_in[9];
  const float* proj_w2 = (const float*)d_in[10];
  const float* proj_b2 = (const float*)d_in[11];
  const float* rpb2    = (const float*)d_in[12];
  const float* ln2_g   = (const float*)d_in[13];
  const float* ln2_b   = (const float*)d_in[14];
  const float* fc1_w   = (const float*)d_in[15];
  const float* fc1_b   = (const float*)d_in[16];
  const float* fc2_w   = (const float*)d_in[17];
  const float* fc2_b   = (const float*)d_in[18];
  float* out = (float*)d_out;

  // workspace carve-up (bytes, all 256B-aligned)
  char* wsb = (char*)d_ws;
  unsigned short* xn    = (unsigned short*)(wsb);              // N*128 bf16 (1,605,632)
  unsigned short* qkv1  = (unsigned short*)(wsb + 1605632);    // N*384 bf16 (4,816,896)
  unsigned short* qkv2  = (unsigned short*)(wsb + 6422528);    // N*384 bf16
  unsigned short* attn1 = (unsigned short*)(wsb + 11239424);   // N*128 bf16
  unsigned short* attn2 = (unsigned short*)(wsb + 12845056);   // N*128 bf16
  float*          x2    = (float*)(wsb + 14450688);            // N*128 f32  (3,211,264)
  unsigned short* hbuf  = (unsigned short*)(wsb + 17661952);   // N*256 bf16 (3,211,264)

  ln1_kernel<<<98, 256, 0, stream>>>(x, ln1_g, ln1_b, xn);
  qkv_mfma<<<dim3(98, 12), 256, 0, stream>>>(xn, qkv_w1, qkv_b1, qkv1,
                                             qkv_w2, qkv_b2, qkv2);
  natten_fused<<<1568, 256, 0, stream>>>(qkv1, rpb1, attn1, qkv2, rpb2, attn2);
  proj_mfma<<<dim3(98, 2), 256, 0, stream>>>(attn1, proj_w1, proj_b1,
                                             attn2, proj_w2, proj_b2, x, x2);
  fc1ln_mfma<<<dim3(98, 4), 256, 0, stream>>>(x2, ln2_g, ln2_b, fc1_w, fc1_b, hbuf);
  fc2_mfma<<<dim3(98, 2), 256, 0, stream>>>(hbuf, fc2_w, fc2_b, x2, out);
}

// Round 12
// 157.318 us; speedup vs baseline: 1.1464x; 1.0066x over previous
//
#include <hip/hip_runtime.h>
#include <hip/hip_bf16.h>

// Problem constants (B=2, C=128, H=W=56)
#define BATCH 2
#define CH    128
#define HH    56
#define WW    56
#define HWS   3136        // H*W
#define NPOS  6272        // B*H*W
#define HEADS 4
#define HD    32

using f32x4 = __attribute__((ext_vector_type(4))) float;
using s16x8 = __attribute__((ext_vector_type(8))) short;

// fp32 -> bf16 round-to-nearest-even
__device__ __forceinline__ unsigned short f2bf(float f) {
  unsigned u = __builtin_bit_cast(unsigned, f);
  u += 0x7FFFu + ((u >> 16) & 1u);
  return (unsigned short)(u >> 16);
}
__device__ __forceinline__ unsigned pack2bf(float a, float b) {
  return (unsigned)f2bf(a) | ((unsigned)f2bf(b) << 16);
}
// 4 packed bf16 (uint2) -> float4
__device__ __forceinline__ float4 bf4tof(uint2 u) {
  float4 r;
  r.x = __builtin_bit_cast(float, u.x << 16);
  r.y = __builtin_bit_cast(float, u.x & 0xFFFF0000u);
  r.z = __builtin_bit_cast(float, u.y << 16);
  r.w = __builtin_bit_cast(float, u.y & 0xFFFF0000u);
  return r;
}

// ---------------------------------------------------------------------------
// LN1: x (NCHW fp32) -> xn (N x C, bf16)   [R7-verified]
// ---------------------------------------------------------------------------
__global__ __launch_bounds__(256) void ln1_kernel(const float* __restrict__ x,
                                                  const float* __restrict__ g,
                                                  const float* __restrict__ be,
                                                  unsigned short* __restrict__ out) {
  __shared__ float tile[128 * 65];
  __shared__ float mu_s[64];
  __shared__ float rs_s[64];
  const int p0 = blockIdx.x * 64;
  const int b  = (p0 >= HWS) ? 1 : 0;
  const int s0 = p0 - b * HWS;
  const int tid = threadIdx.x;

  for (int idx = tid; idx < 8192; idx += 256) {
    int c = idx >> 6, p = idx & 63;
    tile[c * 65 + p] = x[(size_t)(b * CH + c) * HWS + s0 + p];
  }
  __syncthreads();
  {
    int p = tid >> 2, q = tid & 3;
    float sum = 0.f, sq = 0.f;
#pragma unroll
    for (int t = 0; t < 32; ++t) {
      float v = tile[(q * 32 + t) * 65 + p];
      sum += v; sq += v * v;
    }
    sum += __shfl_xor(sum, 1); sq += __shfl_xor(sq, 1);
    sum += __shfl_xor(sum, 2); sq += __shfl_xor(sq, 2);
    float mu  = sum * 0.0078125f;
    float var = sq * 0.0078125f - mu * mu;
    float rs  = rsqrtf(var + 1e-5f);
    if (q == 0) { mu_s[p] = mu; rs_s[p] = rs; }
  }
  __syncthreads();
  for (int idx = tid; idx < 4096; idx += 256) {
    int nl = idx >> 6, c2 = idx & 63;
    int c0 = 2 * c2;
    float v0 = (tile[c0 * 65 + nl] - mu_s[nl]) * rs_s[nl] * g[c0] + be[c0];
    float v1 = (tile[(c0 + 1) * 65 + nl] - mu_s[nl]) * rs_s[nl] * g[c0 + 1] + be[c0 + 1];
    reinterpret_cast<unsigned*>(out)[(size_t)(p0 + nl) * 64 + c2] = pack2bf(v0, v1);
  }
}

// ---------------------------------------------------------------------------
// MFMA tile helpers.  LDS bf16 tiles, byte ^= (row&7)<<4 XOR swizzle.
// Generalized to arbitrary K-extent per tile (kElems = 64/128/256).
// 256 threads = 4 waves; wave w -> quadrant (w>>1, w&1); 2x2 16x16x32 frags.
// C/D layout: col = lane&15, row = (lane>>4)*4 + reg.
// ---------------------------------------------------------------------------
__device__ __forceinline__ void stage_tile(const unsigned short* __restrict__ src,
                                           int stride, int row0, int kElems,
                                           int tid, char* dstB) {
  const int upr = kElems >> 3;            // 16B units per row
  const int total = 64 * upr;
#pragma unroll
  for (int u = tid; u < total; u += 256) {
    int row = u / upr;
    int ku  = u % upr;
    int byte = row * (kElems << 1) + (ku << 4);
    byte ^= (row & 7) << 4;
    *reinterpret_cast<uint4*>(dstB + byte) =
        *reinterpret_cast<const uint4*>(src + (size_t)(row0 + row) * stride + (ku << 3));
  }
}

// fp32 source, converted to bf16 on the fly.  [R8-verified conversion]
__device__ __forceinline__ void stage_tile_f32(const float* __restrict__ src,
                                               int stride, int row0, int kElems,
                                               int tid, char* dstB) {
  const int upr = kElems >> 3;
  const int total = 64 * upr;
#pragma unroll
  for (int u = tid; u < total; u += 256) {
    int row = u / upr;
    int ku  = u % upr;
    int byte = row * (kElems << 1) + (ku << 4);
    byte ^= (row & 7) << 4;
    const float* s = src + (size_t)(row0 + row) * stride + (ku << 3);
    float4 va = *reinterpret_cast<const float4*>(s);
    float4 vb = *reinterpret_cast<const float4*>(s + 4);
    uint4 o;
    o.x = pack2bf(va.x, va.y);
    o.y = pack2bf(va.z, va.w);
    o.z = pack2bf(vb.x, vb.y);
    o.w = pack2bf(vb.z, vb.w);
    *reinterpret_cast<uint4*>(dstB + byte) = o;
  }
}

// One K=64 slab: A rows at aStrideB bytes (+aKoffB), W rows at wStrideB (+wKoffB).
__device__ __forceinline__ void tile_compute2(const char* AsB, int aStrideB, int aKoffB,
                                              const char* WsB, int wStrideB, int wKoffB,
                                              int lane, int wr, int wc,
                                              f32x4 (&acc)[2][2]) {
  const int r_lo = lane & 15, kg = lane >> 4;
#pragma unroll
  for (int ks = 0; ks < 2; ++ks) {
    const int ko = ks * 64 + kg * 16;
    const int koffA = aKoffB + ko;
    const int koffW = wKoffB + ko;
    s16x8 a[2], bf[2];
#pragma unroll
    for (int fi = 0; fi < 2; ++fi) {
      int row = wr * 32 + fi * 16 + r_lo;
      int byte = row * aStrideB + koffA; byte ^= (row & 7) << 4;
      a[fi] = *reinterpret_cast<const s16x8*>(AsB + byte);
    }
#pragma unroll
    for (int ci = 0; ci < 2; ++ci) {
      int row = wc * 32 + ci * 16 + r_lo;
      int byte = row * wStrideB + koffW; byte ^= (row & 7) << 4;
      bf[ci] = *reinterpret_cast<const s16x8*>(WsB + byte);
    }
#pragma unroll
    for (int fi = 0; fi < 2; ++fi)
#pragma unroll
      for (int ci = 0; ci < 2; ++ci)
        acc[fi][ci] = __builtin_amdgcn_mfma_f32_16x16x32_bf16(a[fi], bf[ci], acc[fi][ci], 0, 0, 0);
  }
}

__device__ __forceinline__ float gelu_exact(float v) {
  return 0.5f * v * (1.0f + erff(v * 0.70710678118654752f));
}

// ---------------------------------------------------------------------------
// Fused qkv GEMM (both branches).  A = xn (N x 128 bf16), W fp32 on the fly.
// Single-shot stage (A 16KB + W 16KB), ONE barrier.  grid (98, 12).
// ---------------------------------------------------------------------------
__global__ __launch_bounds__(256) void qkv_mfma(const unsigned short* __restrict__ A,
                                                const float* __restrict__ W1f,
                                                const float* __restrict__ b1,
                                                unsigned short* __restrict__ o1,
                                                const float* __restrict__ W2f,
                                                const float* __restrict__ b2,
                                                unsigned short* __restrict__ o2) {
  __shared__ char AsB[16384];   // 64 x 128k bf16, 256B rows
  __shared__ char WsB[16384];
  const int tid = threadIdx.x;
  const int lane = tid & 63, w = tid >> 6, wr = w >> 1, wc = w & 1;
  const int p0 = blockIdx.x * 64;
  const int yy = blockIdx.y;
  const bool first = yy < 6;
  const float* Wf = first ? W1f : W2f;
  const float* bias = first ? b1 : b2;
  unsigned short* outp = first ? o1 : o2;
  const int n0 = (first ? yy : yy - 6) * 64;

  stage_tile(A, 128, p0, 128, tid, AsB);
  stage_tile_f32(Wf, 128, n0, 128, tid, WsB);

  f32x4 acc[2][2];
#pragma unroll
  for (int i = 0; i < 2; ++i)
#pragma unroll
    for (int j = 0; j < 2; ++j) acc[i][j] = (f32x4){0.f, 0.f, 0.f, 0.f};

  __syncthreads();
  tile_compute2(AsB, 256, 0,   WsB, 256, 0,   lane, wr, wc, acc);
  tile_compute2(AsB, 256, 128, WsB, 256, 128, lane, wr, wc, acc);

  const int r_lo = lane & 15, kg = lane >> 4;
#pragma unroll
  for (int ci = 0; ci < 2; ++ci) {
    int col = n0 + wc * 32 + ci * 16 + r_lo;
    float bc = bias[col];
#pragma unroll
    for (int fi = 0; fi < 2; ++fi) {
      int row0 = p0 + wr * 32 + fi * 16 + kg * 4;
#pragma unroll
      for (int r = 0; r < 4; ++r)
        outp[(size_t)(row0 + r) * 384 + col] = f2bf(acc[fi][ci][r] + bc);
    }
  }
}

// ---------------------------------------------------------------------------
// x2 (N x C fp32) = x(NCHW res) + attn1@W1^T + b1 + attn2@W2^T + b2
// Single-shot stage of BOTH branches (64KB LDS).  ONE barrier.
// ---------------------------------------------------------------------------
__global__ __launch_bounds__(256) void proj_mfma(const unsigned short* __restrict__ A1,
                                                 const float* __restrict__ W1f,
                                                 const float* __restrict__ b1,
                                                 const unsigned short* __restrict__ A2,
                                                 const float* __restrict__ W2f,
                                                 const float* __restrict__ b2,
                                                 const float* __restrict__ xres,
                                                 float* __restrict__ x2out) {
  __shared__ char A1B[16384];
  __shared__ char W1B[16384];
  __shared__ char A2B[16384];
  __shared__ char W2B[16384];
  const int tid = threadIdx.x;
  const int lane = tid & 63, w = tid >> 6, wr = w >> 1, wc = w & 1;
  const int p0 = blockIdx.x * 64, n0 = blockIdx.y * 64;
  const int bb = (p0 >= HWS) ? 1 : 0;
  const int s0 = p0 - bb * HWS;

  stage_tile(A1, 128, p0, 128, tid, A1B);
  stage_tile_f32(W1f, 128, n0, 128, tid, W1B);
  stage_tile(A2, 128, p0, 128, tid, A2B);
  stage_tile_f32(W2f, 128, n0, 128, tid, W2B);

  f32x4 acc[2][2];
#pragma unroll
  for (int i = 0; i < 2; ++i)
#pragma unroll
    for (int j = 0; j < 2; ++j) acc[i][j] = (f32x4){0.f, 0.f, 0.f, 0.f};

  __syncthreads();
  tile_compute2(A1B, 256, 0,   W1B, 256, 0,   lane, wr, wc, acc);
  tile_compute2(A1B, 256, 128, W1B, 256, 128, lane, wr, wc, acc);
  tile_compute2(A2B, 256, 0,   W2B, 256, 0,   lane, wr, wc, acc);
  tile_compute2(A2B, 256, 128, W2B, 256, 128, lane, wr, wc, acc);

  const int r_lo = lane & 15, kg = lane >> 4;
#pragma unroll
  for (int ci = 0; ci < 2; ++ci) {
    int col = n0 + wc * 32 + ci * 16 + r_lo;
    float bc = b1[col] + b2[col];
#pragma unroll
    for (int fi = 0; fi < 2; ++fi) {
      int rloc = wr * 32 + fi * 16 + kg * 4;
      float4 xr = *reinterpret_cast<const float4*>(
          &xres[(size_t)(bb * CH + col) * HWS + s0 + rloc]);
      int row0 = p0 + rloc;
      x2out[(size_t)(row0 + 0) * CH + col] = acc[fi][ci][0] + bc + xr.x;
      x2out[(size_t)(row0 + 1) * CH + col] = acc[fi][ci][1] + bc + xr.y;
      x2out[(size_t)(row0 + 2) * CH + col] = acc[fi][ci][2] + bc + xr.z;
      x2out[(size_t)(row0 + 3) * CH + col] = acc[fi][ci][3] + bc + xr.w;
    }
  }
}

// ---------------------------------------------------------------------------
// fc1 with fused LN2: A = LN(x2) built into LDS (bf16, swizzled), W staged
// full-K.  ONE barrier.  grid (98, 4).
// ---------------------------------------------------------------------------
__global__ __launch_bounds__(256) void fc1ln_mfma(const float* __restrict__ x2,
                                                  const float* __restrict__ g,
                                                  const float* __restrict__ be,
                                                  const float* __restrict__ Wf,
                                                  const float* __restrict__ bias,
                                                  unsigned short* __restrict__ out) {
  __shared__ char AsB[16384];   // 64 rows x 128 k bf16 (256 B/row), swizzled
  __shared__ char WsB[16384];
  const int tid = threadIdx.x;
  const int lane = tid & 63, w = tid >> 6, wr = w >> 1, wc = w & 1;
  const int p0 = blockIdx.x * 64, n0 = blockIdx.y * 64;
  // --- LN2 into AsB: 4 threads per row ---
  {
    const int p = tid >> 2, q = tid & 3;
    const float* row = x2 + (size_t)(p0 + p) * CH + q * 32;
    float4 v[8];
    float sum = 0.f, sq = 0.f;
#pragma unroll
    for (int t = 0; t < 8; ++t) {
      v[t] = *reinterpret_cast<const float4*>(row + t * 4);
      sum += v[t].x + v[t].y + v[t].z + v[t].w;
      sq  += v[t].x * v[t].x + v[t].y * v[t].y + v[t].z * v[t].z + v[t].w * v[t].w;
    }
    sum += __shfl_xor(sum, 1); sq += __shfl_xor(sq, 1);
    sum += __shfl_xor(sum, 2); sq += __shfl_xor(sq, 2);
    float mu = sum * 0.0078125f;
    float rs = rsqrtf(sq * 0.0078125f - mu * mu + 1e-5f);
#pragma unroll
    for (int t = 0; t < 8; t += 2) {
      int d0 = q * 32 + t * 4;
      float4 g0 = *reinterpret_cast<const float4*>(g + d0);
      float4 g1 = *reinterpret_cast<const float4*>(g + d0 + 4);
      float4 b0 = *reinterpret_cast<const float4*>(be + d0);
      float4 b1v = *reinterpret_cast<const float4*>(be + d0 + 4);
      uint4 o;
      o.x = pack2bf((v[t].x - mu) * rs * g0.x + b0.x, (v[t].y - mu) * rs * g0.y + b0.y);
      o.y = pack2bf((v[t].z - mu) * rs * g0.z + b0.z, (v[t].w - mu) * rs * g0.w + b0.w);
      o.z = pack2bf((v[t+1].x - mu) * rs * g1.x + b1v.x, (v[t+1].y - mu) * rs * g1.y + b1v.y);
      o.w = pack2bf((v[t+1].z - mu) * rs * g1.z + b1v.z, (v[t+1].w - mu) * rs * g1.w + b1v.w);
      int byte = p * 256 + q * 64 + (t >> 1) * 16;
      byte ^= (p & 7) << 4;
      *reinterpret_cast<uint4*>(AsB + byte) = o;
    }
  }
  stage_tile_f32(Wf, 128, n0, 128, tid, WsB);

  f32x4 acc[2][2];
#pragma unroll
  for (int i = 0; i < 2; ++i)
#pragma unroll
    for (int j = 0; j < 2; ++j) acc[i][j] = (f32x4){0.f, 0.f, 0.f, 0.f};

  __syncthreads();
  tile_compute2(AsB, 256, 0,   WsB, 256, 0,   lane, wr, wc, acc);
  tile_compute2(AsB, 256, 128, WsB, 256, 128, lane, wr, wc, acc);

  const int r_lo = lane & 15, kg = lane >> 4;
#pragma unroll
  for (int ci = 0; ci < 2; ++ci) {
    int col = n0 + wc * 32 + ci * 16 + r_lo;
    float bc = bias[col];
#pragma unroll
    for (int fi = 0; fi < 2; ++fi) {
      int row0 = p0 + wr * 32 + fi * 16 + kg * 4;
#pragma unroll
      for (int r = 0; r < 4; ++r)
        out[(size_t)(row0 + r) * 256 + col] = f2bf(gelu_exact(acc[fi][ci][r] + bc));
    }
  }
}

// ---------------------------------------------------------------------------
// d_out (NCHW fp32) = x2 + h @ fc2_w^T + fc2_b ;  K = 256.
// Single-shot stage (A 32KB + W 32KB).  ONE barrier.
// ---------------------------------------------------------------------------
__global__ __launch_bounds__(256) void fc2_mfma(const unsigned short* __restrict__ A,
                                                const float* __restrict__ Wf,
                                                const float* __restrict__ bias,
                                                const float* __restrict__ x2,
                                                float* __restrict__ out) {
  __shared__ char AsB[32768];   // 64 x 256k bf16, 512B rows
  __shared__ char WsB[32768];
  const int tid = threadIdx.x;
  const int lane = tid & 63, w = tid >> 6, wr = w >> 1, wc = w & 1;
  const int p0 = blockIdx.x * 64, n0 = blockIdx.y * 64;
  const int bb = (p0 >= HWS) ? 1 : 0;
  const int s0 = p0 - bb * HWS;

  stage_tile(A, 256, p0, 256, tid, AsB);
  stage_tile_f32(Wf, 256, n0, 256, tid, WsB);

  f32x4 acc[2][2];
#pragma unroll
  for (int i = 0; i < 2; ++i)
#pragma unroll
    for (int j = 0; j < 2; ++j) acc[i][j] = (f32x4){0.f, 0.f, 0.f, 0.f};

  __syncthreads();
#pragma unroll
  for (int kb = 0; kb < 4; ++kb)
    tile_compute2(AsB, 512, kb * 128, WsB, 512, kb * 128, lane, wr, wc, acc);

  const int r_lo = lane & 15, kg = lane >> 4;
#pragma unroll
  for (int ci = 0; ci < 2; ++ci) {
    int col = n0 + wc * 32 + ci * 16 + r_lo;
    float bc = bias[col];
#pragma unroll
    for (int fi = 0; fi < 2; ++fi) {
      int rloc = wr * 32 + fi * 16 + kg * 4;
      int row0 = p0 + rloc;
      float4 o;
      o.x = acc[fi][ci][0] + bc + x2[(size_t)(row0 + 0) * CH + col];
      o.y = acc[fi][ci][1] + bc + x2[(size_t)(row0 + 1) * CH + col];
      o.z = acc[fi][ci][2] + bc + x2[(size_t)(row0 + 2) * CH + col];
      o.w = acc[fi][ci][3] + bc + x2[(size_t)(row0 + 3) * CH + col];
      *reinterpret_cast<float4*>(&out[(size_t)(bb * CH + col) * HWS + s0 + rloc]) = o;
    }
  }
}

// ---------------------------------------------------------------------------
// Neighborhood attention, 8 lanes per output, ONLINE softmax (defer-max,
// THR=8; rescale branch is uniform within each 8-lane group since the
// butterfly-reduced score is bit-identical across the group).  Fused
// QK/softmax/PV single pass kills the sc[NW*NW] register array.
// ---------------------------------------------------------------------------
template <int NW>
__device__ __forceinline__ void natten_body(const unsigned short* __restrict__ qkvb,
                                            const float* __restrict__ rpb,
                                            unsigned short* __restrict__ out,
                                            int blk, int tid) {
  const int g   = blk * 32 + (tid >> 3);
  const int sub = tid & 7;
  const int j  = g % WW;
  const int t1 = g / WW;
  const int i  = t1 % HH;
  const int t2 = t1 / HH;
  const int h  = t2 & 3;
  const int b  = t2 >> 2;
  const int n  = b * HWS + i * WW + j;

  const float scale = 0.17677669529663687f;  // 1/sqrt(32)
  float4 q = bf4tof(*reinterpret_cast<const uint2*>(qkvb + (size_t)n * 384 + h * 32 + sub * 4));
  q.x *= scale; q.y *= scale; q.z *= scale; q.w *= scale;

  const int si = min(max(i - NW / 2, 0), HH - NW);
  const int sj = min(max(j - NW / 2, 0), WW - NW);
  const float* rb = rpb + h * (2 * NW - 1) * (2 * NW - 1)
                    + (NW - 1 - (i - si)) * (2 * NW - 1) + (NW - 1 - (j - sj));
  float m = -1e30f, l = 0.f;
  float4 o = make_float4(0.f, 0.f, 0.f, 0.f);
#pragma unroll
  for (int ki = 0; ki < NW; ++ki) {
    const unsigned short* rowp =
        qkvb + (size_t)(b * HWS + (si + ki) * WW + sj) * 384 + 128 + h * 32 + sub * 4;
#pragma unroll
    for (int kj = 0; kj < NW; ++kj) {
      float4 k4 = bf4tof(*reinterpret_cast<const uint2*>(rowp + kj * 384));
      float p = q.x * k4.x + q.y * k4.y + q.z * k4.z + q.w * k4.w;
      p += __shfl_xor(p, 1);
      p += __shfl_xor(p, 2);
      p += __shfl_xor(p, 4);
      p += rb[ki * (2 * NW - 1) + kj];
      if (p > m + 8.f) {                  // defer-max rescale (rarely taken)
        float r = __expf(m - p);          // first hit: exp(-inf)=0 zeroes l,o
        l *= r; o.x *= r; o.y *= r; o.z *= r; o.w *= r;
        m = p;
      }
      float e = __expf(p - m);
      l += e;
      float4 v4 = bf4tof(*reinterpret_cast<const uint2*>(rowp + kj * 384 + 128));
      o.x = fmaf(e, v4.x, o.x);
      o.y = fmaf(e, v4.y, o.y);
      o.z = fmaf(e, v4.z, o.z);
      o.w = fmaf(e, v4.w, o.w);
    }
  }
  float inv = 1.0f / l;
  uint2 ov;
  ov.x = pack2bf(o.x * inv, o.y * inv);
  ov.y = pack2bf(o.z * inv, o.w * inv);
  *reinterpret_cast<uint2*>(out + (size_t)n * CH + h * 32 + sub * 4) = ov;
}

// Bijective XCD swizzle (m204 form; 1568 = 8 x 196 exactly): each XCD gets
// 196 consecutive work-ids -> its gather footprint (~0.8 MB) is L2-resident.
__global__ __launch_bounds__(256) void natten_fused(const unsigned short* __restrict__ qkv1,
                                                    const float* __restrict__ rpb1,
                                                    unsigned short* __restrict__ a1,
                                                    const unsigned short* __restrict__ qkv2,
                                                    const float* __restrict__ rpb2,
                                                    unsigned short* __restrict__ a2) {
  const int swz = (blockIdx.x & 7) * 196 + (blockIdx.x >> 3);
  if (swz < 784) natten_body<7>(qkv1, rpb1, a1, swz, threadIdx.x);
  else           natten_body<5>(qkv2, rpb2, a2, swz - 784, threadIdx.x);
}

// ---------------------------------------------------------------------------
extern "C" void kernel_launch(void* const* d_in, const int* in_sizes, int n_in,
                              void* d_out, int out_size, void* d_ws, size_t ws_size,
                              hipStream_t stream) {
  const float* x       = (const float*)d_in[0];
  const float* ln1_g   = (const float*)d_in[1];
  const float* ln1_b   = (const float*)d_in[2];
  const float* qkv_w1  = (const float*)d_in[3];
  const float* qkv_b1  = (const float*)d_in[4];
  const float* proj_w1 = (const float*)d_in[5];
  const float* proj_b1 = (const float*)d_in[6];
  const float* rpb1    = (const float*)d_in[7];
  const float* qkv_w2  = (const float*)d_in[8];
  const float* qkv_b2  = (const float*)d_in[9];
  const float* proj_w2 = (const float*)d_in[10];
  const float* proj_b2 = (const float*)d_in[11];
  const float* rpb2    = (const float*)d_in[12];
  const float* ln2_g   = (const float*)d_in[13];
  const float* ln2_b   = (const float*)d_in[14];
  const float* fc1_w   = (const float*)d_in[15];
  const float* fc1_b   = (const float*)d_in[16];
  const float* fc2_w   = (const float*)d_in[17];
  const float* fc2_b   = (const float*)d_in[18];
  float* out = (float*)d_out;

  // workspace carve-up (bytes, all 256B-aligned)
  char* wsb = (char*)d_ws;
  unsigned short* xn    = (unsigned short*)(wsb);              // N*128 bf16 (1,605,632)
  unsigned short* qkv1  = (unsigned short*)(wsb + 1605632);    // N*384 bf16 (4,816,896)
  unsigned short* qkv2  = (unsigned short*)(wsb + 6422528);    // N*384 bf16
  unsigned short* attn1 = (unsigned short*)(wsb + 11239424);   // N*128 bf16
  unsigned short* attn2 = (unsigned short*)(wsb + 12845056);   // N*128 bf16
  float*          x2    = (float*)(wsb + 14450688);            // N*128 f32  (3,211,264)
  unsigned short* hbuf  = (unsigned short*)(wsb + 17661952);   // N*256 bf16 (3,211,264)

  ln1_kernel<<<98, 256, 0, stream>>>(x, ln1_g, ln1_b, xn);
  qkv_mfma<<<dim3(98, 12), 256, 0, stream>>>(xn, qkv_w1, qkv_b1, qkv1,
                                             qkv_w2, qkv_b2, qkv2);
  natten_fused<<<1568, 256, 0, stream>>>(qkv1, rpb1, attn1, qkv2, rpb2, attn2);
  proj_mfma<<<dim3(98, 2), 256, 0, stream>>>(attn1, proj_w1, proj_b1,
                                             attn2, proj_w2, proj_b2, x, x2);
  fc1ln_mfma<<<dim3(98, 4), 256, 0, stream>>>(x2, ln2_g, ln2_b, fc1_w, fc1_b, hbuf);
  fc2_mfma<<<dim3(98, 2), 256, 0, stream>>>(hbuf, fc2_w, fc2_b, x2, out);
}